// Round 8
// baseline (35218.088 us; speedup 1.0000x reference)
//
#include <hip/hip_runtime.h>
#include <hip/hip_fp16.h>

#define BB   32
#define TENC 256
#define EE   512
#define TDEC 200
#define NM   80
#define HH   1024
#define AA   128
#define GG   4096
#define K1   1792   // x(256)|ctx(512)|h1(1024)
#define K2   2048   // h1|h2

typedef _Float16 h8v __attribute__((ext_vector_type(8)));

__device__ __forceinline__ float sigf(float x){ return 1.0f/(1.0f + __expf(-x)); }
__device__ __forceinline__ float tanhfast(float x){ return 1.0f - 2.0f/(1.0f + __expf(2.0f*x)); }

// ---------------- precompute kernels (unchanged from R7, all compile) ----------------

__global__ void k_zero(float* __restrict__ p, int n){
    int i = blockIdx.x*blockDim.x + threadIdx.x;
    if(i < n) p[i] = 0.f;
}

__global__ void k_cvt_half(const float* __restrict__ src, __half* __restrict__ dst, int n){
    int i = blockIdx.x*blockDim.x + threadIdx.x;
    int stride = gridDim.x*blockDim.x;
    for(; i<n; i+=stride) dst[i] = __float2half(src[i]);
}

__global__ __launch_bounds__(256) void k_transpose2(const float* __restrict__ src,
                                                    _Float16* __restrict__ dst,
                                                    int K, int C, int dstStride, int kOff, int pack){
    __shared__ float tile[32][33];
    const int tid = threadIdx.x;
    const int c0 = blockIdx.x*32, k0 = blockIdx.y*32;
    const int cl = tid & 31, r8 = tid >> 5;
    #pragma unroll
    for(int i=0;i<4;i++){
        const int k = k0 + r8 + i*8;
        if(k < K && c0+cl < C) tile[r8 + i*8][cl] = src[(size_t)k*C + c0 + cl];
    }
    __syncthreads();
    const int kl = tid & 31, c8 = tid >> 5;
    #pragma unroll
    for(int i=0;i<4;i++){
        const int c = c0 + c8 + i*8;
        if(c < C && k0+kl < K){
            const int p = pack ? ((c & 1023)*4 + (c >> 10)) : c;
            dst[(size_t)p*dstStride + kOff + k0 + kl] = (_Float16)tile[kl][c8 + i*8];
        }
    }
}

__global__ __launch_bounds__(128) void k_proc_enc(const float* __restrict__ inputs,
                                                  const float* __restrict__ Wenc,
                                                  __half* __restrict__ pe_h){
    const int row = blockIdx.x;
    const int a   = threadIdx.x;
    const float* in = inputs + (size_t)row*EE;
    float acc = 0.f;
    for(int k=0;k<EE;k++) acc = fmaf(in[k], Wenc[k*AA + a], acc);
    pe_h[(size_t)row*AA + a] = __float2half(acc);
}

__global__ __launch_bounds__(320) void k_pip(const float* __restrict__ inputs,
                                             const float* __restrict__ Wp_c,
                                             __half* __restrict__ PIP){
    const int b = blockIdx.x >> 6, t4 = (blockIdx.x & 63)*4;
    __shared__ float xs[4*EE];
    const int tid = threadIdx.x;
    for(int i=tid; i<4*EE; i+=320) xs[i] = inputs[((size_t)b*TENC + t4)*EE + i];
    __syncthreads();
    const int tl = tid/80, m = tid%80;
    float acc = 0.f;
    for(int k=0;k<EE;k++) acc = fmaf(xs[tl*EE + k], Wp_c[k*NM + m], acc);
    PIP[((size_t)b*TENC + t4 + tl)*NM + m] = __float2half(acc);
}

__global__ __launch_bounds__(256) void k_prenet(const float* __restrict__ pmels,
                                                const float* __restrict__ pw1, const float* __restrict__ pb1,
                                                const float* __restrict__ pw2, const float* __restrict__ pb2,
                                                float* __restrict__ XS1){
    const int t = blockIdx.x;
    __shared__ float pm[BB*NM];
    __shared__ float h1s[BB*256];
    const int tid = threadIdx.x;
    for(int el=tid; el<BB*NM; el+=256){
        const int b = el/NM, m = el%NM;
        pm[el] = (t==0) ? 0.f : pmels[(size_t)(b*NM + m)*TDEC + (t-1)];
    }
    __syncthreads();
    const int a = tid;
    float acc[BB];
    #pragma unroll
    for(int b=0;b<BB;b++) acc[b]=0.f;
    for(int m=0;m<NM;m++){
        const float w = pw1[m*256 + a];
        #pragma unroll
        for(int b=0;b<BB;b++) acc[b] = fmaf(pm[b*NM+m], w, acc[b]);
    }
    {
        const float bias = pb1[a];
        for(int b=0;b<BB;b++) h1s[b*256+a] = fmaxf(acc[b]+bias, 0.f);
    }
    __syncthreads();
    #pragma unroll
    for(int b=0;b<BB;b++) acc[b]=0.f;
    for(int k=0;k<256;k++){
        const float w = pw2[k*256 + a];
        #pragma unroll
        for(int b=0;b<BB;b++) acc[b] = fmaf(h1s[b*256+k], w, acc[b]);
    }
    {
        const float bias = pb2[a];
        #pragma unroll
        for(int b=0;b<BB;b++)
            XS1[((size_t)t*BB + b)*K1 + a] = fmaxf(acc[b]+bias, 0.f);
    }
}

__global__ void k_mloc(const float* __restrict__ conv_w, const float* __restrict__ conv_b,
                       const float* __restrict__ W_loc, float* __restrict__ Mloc, float* __restrict__ cbp){
    const int a = threadIdx.x;
    for(int d=0; d<31; d++){
        float s = 0.f;
        for(int ch=0; ch<32; ch++) s = fmaf(conv_w[ch*31 + d], W_loc[ch*AA + a], s);
        Mloc[d*AA + a] = s;
    }
    float s = 0.f;
    for(int ch=0; ch<32; ch++) s = fmaf(conv_b[ch], W_loc[ch*AA + a], s);
    cbp[a] = s;
}

// ---------------- persistent decoder: noinline phases with internal LDS ----------------

// Fused GEMM + LSTM cell (verbatim from R7's compiling k_lstm body).
__device__ __attribute__((noinline)) void lstm_phase(int tid, int bid,
    const float* XS, const _Float16* WT, int K,
    const float* bias, float* cst,
    float* houtA, int strideA, int offA,
    float* houtB, int strideB, int offB)
{
    __shared__ float smem[8320];
    const int b = tid & 31, cs = (tid>>5)&1, kp = tid>>6;
    float acc[8];
    #pragma unroll
    for(int j=0;j<8;j++) acc[j]=0.f;
    const _Float16* wbase = WT + (size_t)(bid*16 + cs*8)*K;

    for(int ck=0; ck<K; ck+=256){
        for(int r=tid; r<2048; r+=512){
            const int bb = r >> 6, kq = (r & 63)*4;
            *(float4*)&smem[bb*260 + kq] = *(const float4*)(XS + (size_t)bb*K + ck + kq);
        }
        __syncthreads();
        const float* xrow = smem + b*260 + kp*32;
        const _Float16* wk = wbase + ck + kp*32;
        #pragma unroll
        for(int kb=0; kb<32; kb+=8){
            const float4 xa = *(const float4*)(xrow + kb);
            const float4 xb = *(const float4*)(xrow + kb + 4);
            #pragma unroll
            for(int j=0;j<8;j++){
                const h8v w8 = *(const h8v*)(wk + (size_t)j*K + kb);
                acc[j] = fmaf((float)w8[0], xa.x, acc[j]);
                acc[j] = fmaf((float)w8[1], xa.y, acc[j]);
                acc[j] = fmaf((float)w8[2], xa.z, acc[j]);
                acc[j] = fmaf((float)w8[3], xa.w, acc[j]);
                acc[j] = fmaf((float)w8[4], xb.x, acc[j]);
                acc[j] = fmaf((float)w8[5], xb.y, acc[j]);
                acc[j] = fmaf((float)w8[6], xb.z, acc[j]);
                acc[j] = fmaf((float)w8[7], xb.w, acc[j]);
            }
        }
        __syncthreads();
    }
    #pragma unroll
    for(int j=0;j<8;j++) smem[(cs*8+j)*32 + b + 512*kp] = acc[j];
    __syncthreads();
    {
        float s = 0.f;
        #pragma unroll
        for(int q=0;q<8;q++) s += smem[tid + 512*q];
        const int p = bid*16 + (tid>>5);
        __syncthreads();
        smem[4608 + tid] = s + bias[(p & 3)*HH + (p >> 2)];
    }
    __syncthreads();
    if(tid < 128){
        const int cl = tid>>5, bb = tid&31;
        const float gi = smem[4608 + (cl*4+0)*32 + bb];
        const float gf = smem[4608 + (cl*4+1)*32 + bb];
        const float gg = smem[4608 + (cl*4+2)*32 + bb];
        const float go = smem[4608 + (cl*4+3)*32 + bb];
        const int cell = bid*4 + cl;
        const int ci = cell*BB + bb;
        const float cn = sigf(gf)*cst[ci] + sigf(gi)*tanhfast(gg);
        cst[ci] = cn;
        const float hv = sigf(go)*tanhfast(cn);
        houtA[(size_t)bb*strideA + offA + cell] = hv;
        if(houtB) houtB[(size_t)bb*strideB + offB + cell] = hv;
    }
}

// q (redundant per b) + energies for a 32-t slice. b=bid&31, ts=bid>>5. 512 threads.
__device__ __attribute__((noinline)) void qe_phase(int tid, int bid,
    const float* XS2cur, const _Float16* WqT, const float* cbp,
    const float* Mloc, const float* ve, const float* awc,
    const __half* pe, float* e_ws)
{
    __shared__ float h2s[1024], qc[512], qf[128], awin[64], ep[64];
    const int b = bid & 31, ts = bid >> 5;
    const int a = tid & 127, tp = tid >> 7;
    for(int i=tid; i<1024; i+=512) h2s[i] = XS2cur[(size_t)b*2048 + 1024 + i];
    if(tid < 62){
        const int g = ts*32 - 15 + tid;
        awin[tid] = (g>=0 && g<TENC) ? awc[b*TENC+g] : 0.f;
    }
    __syncthreads();
    {
        float qa = 0.f;
        const _Float16* wq = WqT + (size_t)a*HH + tp*256;
        const float* hs = h2s + tp*256;
        for(int kb=0; kb<256; kb+=8){
            const h8v w8 = *(const h8v*)(wq + kb);
            #pragma unroll
            for(int i2=0;i2<8;i2++) qa = fmaf((float)w8[i2], hs[kb+i2], qa);
        }
        qc[tp*128 + a] = qa;
    }
    __syncthreads();
    if(tid < 128) qf[tid] = qc[tid] + qc[128+tid] + qc[256+tid] + qc[384+tid] + cbp[tid];
    __syncthreads();
    float mlr[31];
    #pragma unroll
    for(int d=0;d<31;d++) mlr[d] = Mloc[d*AA + a];
    const float ver = ve[a];
    const float qv  = qf[a];
    const int tl0 = tp*8;
    #pragma unroll
    for(int i=0;i<8;i++){
        const int tl = tl0 + i;
        const int t  = ts*32 + tl;
        float s = qv + __half2float(pe[((size_t)(b*TENC + t))*AA + a]);
        #pragma unroll
        for(int d=0;d<31;d++) s = fmaf(awin[tl + d], mlr[d], s);
        float v = tanhfast(s)*ver;
        #pragma unroll
        for(int o=32;o>=1;o>>=1) v += __shfl_xor(v, o);
        if((tid & 63) == 0) ep[tl*2 + ((tid>>6)&1)] = v;
    }
    __syncthreads();
    if(tid < 32) e_ws[b*TENC + ts*32 + tid] = ep[tid*2] + ep[tid*2 + 1];
}

// softmax + awc + ctx (-> next XS1 row) + output projection. bid<32 only. 512 threads.
__device__ __attribute__((noinline)) void attn_phase(int tid, int b,
    const float* XS2cur, const float* e_ws, const __half* inputs_h,
    const __half* PIP, float* awc, float* XS1next,
    const _Float16* WohT, const float* bp, float* out, int t)
{
    __shared__ float aw[TENC], h2s[1024], red1[320], red2[320], sred[16];
    for(int i=tid; i<1024; i+=512) h2s[i] = XS2cur[(size_t)b*2048 + 1024 + i];
    const float e = (tid < TENC) ? e_ws[b*TENC + tid] : -1e30f;
    float mx = e;
    #pragma unroll
    for(int o=32;o>=1;o>>=1) mx = fmaxf(mx, __shfl_xor(mx, o));
    if((tid & 63) == 0) sred[tid>>6] = mx;
    __syncthreads();
    mx = sred[0];
    #pragma unroll
    for(int w=1;w<8;w++) mx = fmaxf(mx, sred[w]);
    const float pex = (tid < TENC) ? __expf(e - mx) : 0.f;
    float sm = pex;
    #pragma unroll
    for(int o=32;o>=1;o>>=1) sm += __shfl_xor(sm, o);
    if((tid & 63) == 0) sred[8 + (tid>>6)] = sm;
    __syncthreads();
    float tot = 0.f;
    #pragma unroll
    for(int w=0;w<8;w++) tot += sred[8+w];
    const float awv = pex / tot;
    if(tid < TENC){ aw[tid] = awv; awc[b*TENC + tid] += awv; }
    __syncthreads();
    {   // ctx: one of 512 channels per thread
        float a0 = 0.f;
        const __half* ib = inputs_h + (size_t)b*TENC*EE + tid;
        for(int tt=0; tt<TENC; tt+=4){
            const float4 w4 = *(const float4*)&aw[tt];
            a0 = fmaf(w4.x, __half2float(ib[(size_t)(tt+0)*EE]), a0);
            a0 = fmaf(w4.y, __half2float(ib[(size_t)(tt+1)*EE]), a0);
            a0 = fmaf(w4.z, __half2float(ib[(size_t)(tt+2)*EE]), a0);
            a0 = fmaf(w4.w, __half2float(ib[(size_t)(tt+3)*EE]), a0);
        }
        XS1next[(size_t)b*K1 + 256 + tid] = a0;
    }
    if(tid < 320){
        const int kh = tid/80, m = tid - kh*80;
        float s1 = 0.f;
        const _Float16* wo = WohT + (size_t)m*HH + kh*256;
        const float* hs = h2s + kh*256;
        for(int kb=0; kb<256; kb+=8){
            const h8v w8 = *(const h8v*)(wo + kb);
            #pragma unroll
            for(int i2=0;i2<8;i2++) s1 = fmaf((float)w8[i2], hs[kb+i2], s1);
        }
        red1[kh*80 + m] = s1;
        float s2 = 0.f;
        const __half* pp = PIP + ((size_t)(b*TENC) + kh*64)*NM + m;
        const float* awp = aw + kh*64;
        for(int tt=0; tt<64; tt++) s2 = fmaf(awp[tt], __half2float(pp[(size_t)tt*NM]), s2);
        red2[kh*80 + m] = s2;
    }
    __syncthreads();
    if(tid < NM){
        float o = bp[tid];
        #pragma unroll
        for(int k4=0;k4<4;k4++) o += red1[k4*80 + tid] + red2[k4*80 + tid];
        out[((size_t)t*BB + b)*NM + tid] = o;
    }
}

// monotonic-count grid barrier; device-scope atomics + threadfence.
__device__ __attribute__((noinline)) void grid_barrier(unsigned int* bar, int tid, int nb, unsigned int target){
    __syncthreads();
    if(tid == 0){
        __threadfence();
        const unsigned arrive = atomicAdd(&bar[0], 1u);
        if(arrive == (unsigned)nb*target - 1u){
            atomicExch(&bar[1], target);
        } else {
            while(atomicOr(&bar[1], 0u) < target){
                __builtin_amdgcn_s_sleep(2);
            }
        }
        __threadfence();
    }
    __syncthreads();
}

__global__ __launch_bounds__(512) void k_decoder(
    const float* __restrict__ XS1, float* __restrict__ XS2,
    const _Float16* __restrict__ W1T, const _Float16* __restrict__ W2T,
    const _Float16* __restrict__ WqT, const _Float16* __restrict__ WohT,
    const float* __restrict__ bl1, const float* __restrict__ bl2, const float* __restrict__ bp,
    const float* __restrict__ Mloc, const float* __restrict__ cbp, const float* __restrict__ ve,
    const __half* __restrict__ pe, const __half* __restrict__ inputs_h, const __half* __restrict__ PIP,
    float* __restrict__ c1, float* __restrict__ c2, float* __restrict__ awc,
    float* __restrict__ e_ws, float* __restrict__ out, unsigned int* __restrict__ bar,
    int ntime)
{
    const int bid = blockIdx.x, tid = threadIdx.x;
    const int nb = gridDim.x;
    unsigned int bt = 0;
    #pragma clang loop unroll(disable)
    for(int t=0; t<ntime; t++){
        const int p = t & 1;
        const float* xs1cur = XS1 + (size_t)t*BB*K1;
        float* xs1next      = (float*)XS1 + (size_t)(t+1)*BB*K1;
        float* xs2p         = XS2 + (size_t)p*BB*K2;
        float* xs2n         = XS2 + (size_t)(1-p)*BB*K2;

        lstm_phase(tid, bid, xs1cur, W1T, K1, bl1, c1,
                   xs2p, K2, 0, xs1next, K1, 768);
        grid_barrier(bar, tid, nb, ++bt);
        lstm_phase(tid, bid, xs2p, W2T, K2, bl2, c2,
                   xs2n, K2, 1024, (float*)0, 0, 0);
        grid_barrier(bar, tid, nb, ++bt);
        qe_phase(tid, bid, xs2n, WqT, cbp, Mloc, ve, awc, pe, e_ws);
        grid_barrier(bar, tid, nb, ++bt);
        if(bid < 32) attn_phase(tid, bid, xs2n, e_ws, inputs_h, PIP, awc, xs1next,
                                WohT, bp, out, t);
        grid_barrier(bar, tid, nb, ++bt);
    }
}

// ---------------- host ----------------

extern "C" void kernel_launch(void* const* d_in, const int* in_sizes, int n_in,
                              void* d_out, int out_size, void* d_ws, size_t ws_size,
                              hipStream_t stream)
{
    const float* inputs = (const float*)d_in[0];
    const float* pmels  = (const float*)d_in[1];
    const float* W_enc  = (const float*)d_in[2];
    const float* W_q    = (const float*)d_in[3];
    const float* conv_w = (const float*)d_in[4];
    const float* conv_b = (const float*)d_in[5];
    const float* W_loc  = (const float*)d_in[6];
    const float* v_e    = (const float*)d_in[7];
    const float* pw1    = (const float*)d_in[8];
    const float* pb1    = (const float*)d_in[9];
    const float* pw2    = (const float*)d_in[10];
    const float* pb2    = (const float*)d_in[11];
    const float* Wi1    = (const float*)d_in[12];
    const float* Wh1    = (const float*)d_in[13];
    const float* bl1    = (const float*)d_in[14];
    const float* Wi2    = (const float*)d_in[15];
    const float* Wh2    = (const float*)d_in[16];
    const float* bl2    = (const float*)d_in[17];
    const float* Wp     = (const float*)d_in[18];
    const float* bp     = (const float*)d_in[19];
    float* out = (float*)d_out;
    (void)in_sizes; (void)n_in; (void)out_size; (void)ws_size;

    char* ws = (char*)d_ws;
    size_t off = 0;
    auto carve = [&](size_t bytes)->char* {
        char* p = ws + off;
        off += (bytes + 255) & ~(size_t)255;
        return p;
    };
    __half*    inputs_h = (__half*)   carve((size_t)BB*TENC*EE*2);
    __half*    pe_h     = (__half*)   carve((size_t)BB*TENC*AA*2);
    __half*    PIP      = (__half*)   carve((size_t)BB*TENC*NM*2);
    float*     XS1      = (float*)    carve((size_t)(TDEC+1)*BB*K1*4);
    _Float16*  W1T      = (_Float16*) carve((size_t)GG*K1*2);
    _Float16*  W2T      = (_Float16*) carve((size_t)GG*K2*2);
    _Float16*  WqT      = (_Float16*) carve((size_t)AA*HH*2);
    _Float16*  WohT     = (_Float16*) carve((size_t)NM*HH*2);
    // zeroed block: XS2 (2 parity) | c1 | c2 | awc | bar
    const int NZ = 2*BB*K2 + HH*BB + HH*BB + BB*TENC + 64;
    float* zblk = (float*)carve((size_t)NZ*4);
    float* XS2 = zblk;
    float* c1  = XS2 + 2*BB*K2;
    float* c2  = c1 + HH*BB;
    float* awc = c2 + HH*BB;
    unsigned int* bar = (unsigned int*)(awc + BB*TENC);
    float* e_ws = (float*)carve((size_t)BB*TENC*4);
    float* Mloc = (float*)carve((size_t)31*AA*4);
    float* cbp  = (float*)carve((size_t)AA*4);

    // ---- one-time precompute (per launch) ----
    k_zero<<<(NZ+255)/256,256,0,stream>>>(zblk, NZ);
    k_zero<<<(BB*K1+255)/256,256,0,stream>>>(XS1, BB*K1);   // row t=0 (prenet fills x part)
    k_cvt_half<<<2048,256,0,stream>>>(inputs, inputs_h, BB*TENC*EE);
    k_proc_enc<<<BB*TENC,128,0,stream>>>(inputs, W_enc, pe_h);
    k_prenet<<<TDEC,256,0,stream>>>(pmels, pw1,pb1,pw2,pb2, XS1);
    k_mloc<<<1,128,0,stream>>>(conv_w, conv_b, W_loc, Mloc, cbp);
    k_transpose2<<<dim3(GG/32,  768/32),256,0,stream>>>(Wi1, W1T, 768,  GG, K1, 0,    1);
    k_transpose2<<<dim3(GG/32, 1024/32),256,0,stream>>>(Wh1, W1T, 1024, GG, K1, 768,  1);
    k_transpose2<<<dim3(GG/32, 1024/32),256,0,stream>>>(Wi2, W2T, 1024, GG, K2, 0,    1);
    k_transpose2<<<dim3(GG/32, 1024/32),256,0,stream>>>(Wh2, W2T, 1024, GG, K2, 1024, 1);
    k_transpose2<<<dim3(AA/32, 1024/32),256,0,stream>>>(W_q, WqT, 1024, AA, HH, 0,    0);
    k_transpose2<<<dim3(3,     1024/32),256,0,stream>>>(Wp,  WohT, 1024, NM, HH, 0,   0);
    k_pip<<<BB*64,320,0,stream>>>(inputs, Wp + (size_t)HH*NM, PIP);

    // ---- persistent decode: grid=256 <= 256 CUs => capacity-guaranteed co-residency ----
    k_decoder<<<dim3(256), dim3(512), 0, stream>>>(
        XS1, XS2, W1T, W2T, WqT, WohT, bl1, bl2, bp, Mloc, cbp, v_e,
        pe_h, inputs_h, PIP, c1, c2, awc, e_ws, out, bar, TDEC);
}